// Round 1
// baseline (2260.322 us; speedup 1.0000x reference)
//
#include <hip/hip_runtime.h>
#include <hip/hip_bf16.h>
#include <math.h>

#define B_    16
#define LQ_   900
#define D_    256
#define NH_   8
#define HD_   32
#define NL_   4
#define NP_   4
#define DFFN_ 2048
#define LIN_  21760

// ---------------------------------------------------------------------------
// elementwise add (float4)
// ---------------------------------------------------------------------------
__global__ __launch_bounds__(256) void add_kernel(const float* __restrict__ a,
                                                  const float* __restrict__ b,
                                                  float* __restrict__ c,
                                                  size_t n4) {
    size_t i = (size_t)blockIdx.x * blockDim.x + threadIdx.x;
    if (i < n4) {
        float4 x = ((const float4*)a)[i];
        float4 y = ((const float4*)b)[i];
        ((float4*)c)[i] = make_float4(x.x + y.x, x.y + y.y, x.z + y.z, x.w + y.w);
    }
}

// ---------------------------------------------------------------------------
// generic GEMM: C[M,N] = A[M,K] @ W[N,K]^T + bias[N] (+res) (+relu)
// 64x64 tile, 256 threads, 4x4 per thread, BK=16
// ---------------------------------------------------------------------------
__global__ __launch_bounds__(256) void gemm_kernel(const float* __restrict__ A,
                                                   const float* __restrict__ W,
                                                   const float* __restrict__ bias,
                                                   const float* __restrict__ res,
                                                   float* __restrict__ C,
                                                   int M, int N, int K, int relu) {
    __shared__ float As[16][68];
    __shared__ float Ws[16][68];
    const int n0 = blockIdx.x * 64;
    const int m0 = blockIdx.y * 64;
    const int t  = threadIdx.x;
    const int lr = t >> 2;          // 0..63 load row
    const int lc = (t & 3) * 4;     // k-col within BK
    const int tm = (t & 15) * 4;    // compute sub-tile
    const int tn = (t >> 4) * 4;

    float acc[4][4] = {};

    for (int k0 = 0; k0 < K; k0 += 16) {
        // stage A tile
        {
            int am = m0 + lr;
            float4 av = make_float4(0.f, 0.f, 0.f, 0.f);
            if (am < M) av = *(const float4*)(A + (size_t)am * K + k0 + lc);
            As[lc + 0][lr] = av.x; As[lc + 1][lr] = av.y;
            As[lc + 2][lr] = av.z; As[lc + 3][lr] = av.w;
        }
        // stage W tile (N is always a multiple of 64)
        {
            float4 wv = *(const float4*)(W + (size_t)(n0 + lr) * K + k0 + lc);
            Ws[lc + 0][lr] = wv.x; Ws[lc + 1][lr] = wv.y;
            Ws[lc + 2][lr] = wv.z; Ws[lc + 3][lr] = wv.w;
        }
        __syncthreads();
        #pragma unroll
        for (int k = 0; k < 16; ++k) {
            float4 a4 = *(const float4*)&As[k][tm];
            float4 b4 = *(const float4*)&Ws[k][tn];
            float a_[4] = {a4.x, a4.y, a4.z, a4.w};
            float b_[4] = {b4.x, b4.y, b4.z, b4.w};
            #pragma unroll
            for (int i = 0; i < 4; ++i)
                #pragma unroll
                for (int j = 0; j < 4; ++j)
                    acc[i][j] += a_[i] * b_[j];
        }
        __syncthreads();
    }

    #pragma unroll
    for (int i = 0; i < 4; ++i) {
        int m = m0 + tm + i;
        if (m >= M) continue;
        #pragma unroll
        for (int j = 0; j < 4; ++j) {
            int n = n0 + tn + j;
            float v = acc[i][j] + bias[n];
            if (res) v += res[(size_t)m * N + n];
            if (relu) v = fmaxf(v, 0.f);
            C[(size_t)m * N + n] = v;
        }
    }
}

// ---------------------------------------------------------------------------
// flash attention fp32: Q,K,V laid out (B, LQ, D), head slice h*32..h*32+31
// block = 256 threads handles one (b, h, 64-query tile)
// thread: row r = t>>2, lane-group c4 = t&3; keys kidx = c4 + 4j; dims d0=c4*8
// ---------------------------------------------------------------------------
__global__ __launch_bounds__(256) void attn_kernel(const float* __restrict__ Qg,
                                                   const float* __restrict__ Kg,
                                                   const float* __restrict__ Vg,
                                                   float* __restrict__ Og) {
    __shared__ float Ks[64][36];
    __shared__ float Vs[64][36];
    __shared__ float Ps[64][65];

    const int qt = blockIdx.x, h = blockIdx.y, b = blockIdx.z;
    const int q0 = qt * 64;
    const int t  = threadIdx.x;
    const int r  = t >> 2;
    const int c4 = t & 3;
    const int d0 = c4 * 8;

    // Q row in registers (4x redundant per row, fine)
    float qreg[32];
    {
        int qg = q0 + r;
        int qsafe = (qg < LQ_) ? qg : 0;
        const float* src = Qg + ((size_t)(b * LQ_ + qsafe)) * D_ + h * HD_;
        #pragma unroll
        for (int d = 0; d < 32; d += 4) {
            float4 v = *(const float4*)(src + d);
            qreg[d] = v.x; qreg[d + 1] = v.y; qreg[d + 2] = v.z; qreg[d + 3] = v.w;
        }
    }

    float m_i = -1e30f, l_i = 0.f;
    float o_[8] = {};
    const float scale = 0.17677669529663687f;  // 1/sqrt(32)

    for (int kt = 0; kt < 15; ++kt) {
        int k0 = kt * 64;
        // stage K,V rows (row r, cols d0..d0+7)
        {
            int kgr = k0 + r;
            if (kgr < LQ_) {
                const float* ksrc = Kg + ((size_t)(b * LQ_ + kgr)) * D_ + h * HD_ + d0;
                const float* vsrc = Vg + ((size_t)(b * LQ_ + kgr)) * D_ + h * HD_ + d0;
                float4 a = *(const float4*)ksrc, a2 = *(const float4*)(ksrc + 4);
                float4 c = *(const float4*)vsrc, c2 = *(const float4*)(vsrc + 4);
                Ks[r][d0 + 0] = a.x;  Ks[r][d0 + 1] = a.y;  Ks[r][d0 + 2] = a.z;  Ks[r][d0 + 3] = a.w;
                Ks[r][d0 + 4] = a2.x; Ks[r][d0 + 5] = a2.y; Ks[r][d0 + 6] = a2.z; Ks[r][d0 + 7] = a2.w;
                Vs[r][d0 + 0] = c.x;  Vs[r][d0 + 1] = c.y;  Vs[r][d0 + 2] = c.z;  Vs[r][d0 + 3] = c.w;
                Vs[r][d0 + 4] = c2.x; Vs[r][d0 + 5] = c2.y; Vs[r][d0 + 6] = c2.z; Vs[r][d0 + 7] = c2.w;
            } else {
                #pragma unroll
                for (int d = 0; d < 8; ++d) { Ks[r][d0 + d] = 0.f; Vs[r][d0 + d] = 0.f; }
            }
        }
        __syncthreads();

        // scores: this thread covers keys kidx = c4 + 4j, j = 0..15
        float s[16];
        #pragma unroll
        for (int j = 0; j < 16; ++j) {
            int kidx = c4 + 4 * j;
            const float* kr = &Ks[kidx][0];
            float acc = 0.f;
            #pragma unroll
            for (int d = 0; d < 32; d += 4) {
                float4 kv = *(const float4*)(kr + d);
                acc += qreg[d] * kv.x + qreg[d + 1] * kv.y +
                       qreg[d + 2] * kv.z + qreg[d + 3] * kv.w;
            }
            s[j] = acc;
        }
        float rowmax = -1e30f;
        #pragma unroll
        for (int j = 0; j < 16; ++j) {
            int kidx = c4 + 4 * j;
            s[j] = (k0 + kidx < LQ_) ? s[j] * scale : -1e30f;
            rowmax = fmaxf(rowmax, s[j]);
        }
        rowmax = fmaxf(rowmax, __shfl_xor(rowmax, 1));
        rowmax = fmaxf(rowmax, __shfl_xor(rowmax, 2));
        float newm = fmaxf(m_i, rowmax);
        float corr = expf(m_i - newm);
        float rs = 0.f;
        #pragma unroll
        for (int j = 0; j < 16; ++j) {
            float p = expf(s[j] - newm);
            Ps[r][c4 + 4 * j] = p;
            rs += p;
        }
        rs += __shfl_xor(rs, 1);
        rs += __shfl_xor(rs, 2);
        l_i = l_i * corr + rs;
        m_i = newm;
        #pragma unroll
        for (int d = 0; d < 8; ++d) o_[d] *= corr;
        __syncthreads();

        // PV: o[d0..d0+7] += sum_k P[r][k] * V[k][d0..]
        #pragma unroll 8
        for (int k = 0; k < 64; ++k) {
            float p = Ps[r][k];
            const float* vr = &Vs[k][d0];
            float4 v0 = *(const float4*)vr;
            float4 v1 = *(const float4*)(vr + 4);
            o_[0] += p * v0.x; o_[1] += p * v0.y; o_[2] += p * v0.z; o_[3] += p * v0.w;
            o_[4] += p * v1.x; o_[5] += p * v1.y; o_[6] += p * v1.z; o_[7] += p * v1.w;
        }
        __syncthreads();
    }

    if (q0 + r < LQ_) {
        float inv = 1.f / l_i;
        float* dst = Og + ((size_t)(b * LQ_ + q0 + r)) * D_ + h * HD_ + d0;
        #pragma unroll
        for (int d = 0; d < 8; ++d) dst[d] = o_[d] * inv;
    }
}

// ---------------------------------------------------------------------------
// LayerNorm over D=256; one wave per row, 4 rows per block
// ---------------------------------------------------------------------------
__global__ __launch_bounds__(256) void ln_kernel(const float* __restrict__ X,
                                                 const float* __restrict__ g,
                                                 const float* __restrict__ bb,
                                                 float* __restrict__ Y, int M) {
    int row  = blockIdx.x * 4 + (threadIdx.x >> 6);
    int lane = threadIdx.x & 63;
    if (row >= M) return;
    const float* x = X + (size_t)row * D_;
    float4 v = *(const float4*)(x + lane * 4);
    float s = v.x + v.y + v.z + v.w;
    #pragma unroll
    for (int o = 32; o >= 1; o >>= 1) s += __shfl_xor(s, o);
    float mean = s * (1.f / D_);
    float dx0 = v.x - mean, dx1 = v.y - mean, dx2 = v.z - mean, dx3 = v.w - mean;
    float ss = dx0 * dx0 + dx1 * dx1 + dx2 * dx2 + dx3 * dx3;
    #pragma unroll
    for (int o = 32; o >= 1; o >>= 1) ss += __shfl_xor(ss, o);
    float rstd = rsqrtf(ss * (1.f / D_) + 1e-5f);
    float4 gv = *(const float4*)(g + lane * 4);
    float4 bv = *(const float4*)(bb + lane * 4);
    float4 out;
    out.x = dx0 * rstd * gv.x + bv.x;
    out.y = dx1 * rstd * gv.y + bv.y;
    out.z = dx2 * rstd * gv.z + bv.z;
    out.w = dx3 * rstd * gv.w + bv.w;
    *(float4*)(Y + (size_t)row * D_ + lane * 4) = out;
}

// ---------------------------------------------------------------------------
// softmax over 16 contiguous elems per row (B*LQ*NH rows)
// ---------------------------------------------------------------------------
__global__ __launch_bounds__(256) void softmax16_kernel(const float* __restrict__ X,
                                                        float* __restrict__ Y,
                                                        int rows) {
    int r = blockIdx.x * blockDim.x + threadIdx.x;
    if (r >= rows) return;
    const float* x = X + (size_t)r * 16;
    float m = -1e30f;
    #pragma unroll
    for (int i = 0; i < 16; ++i) m = fmaxf(m, x[i]);
    float e[16], s = 0.f;
    #pragma unroll
    for (int i = 0; i < 16; ++i) { e[i] = expf(x[i] - m); s += e[i]; }
    float inv = 1.f / s;
    float* y = Y + (size_t)r * 16;
    #pragma unroll
    for (int i = 0; i < 16; ++i) y[i] = e[i] * inv;
}

// ---------------------------------------------------------------------------
// multi-scale deformable sampling
// one thread per (b,q,h,d); gid = ((b*LQ+q)*NH+h)*HD+d
// ---------------------------------------------------------------------------
__global__ __launch_bounds__(256) void msdeform_kernel(const float* __restrict__ value,
                                                       const float* __restrict__ ref,
                                                       const float* __restrict__ off,
                                                       const float* __restrict__ attw,
                                                       float* __restrict__ out) {
    const int levH[4] = {128, 64, 32, 16};
    const int levW[4] = {128, 64, 32, 16};
    const int levS[4] = {0, 16384, 20480, 21504};

    int gid = blockIdx.x * 256 + threadIdx.x;
    int d   = gid & (HD_ - 1);
    int bqh = gid >> 5;
    int h   = bqh & (NH_ - 1);
    int bq  = bqh >> 3;
    int b   = bq / LQ_;

    const float* refp = ref + (size_t)bq * NL_ * 2;
    const float* offp = off + (size_t)bq * (NH_ * NL_ * NP_ * 2) + h * (NL_ * NP_ * 2);
    const float* awp  = attw + (size_t)bq * (NH_ * NL_ * NP_) + h * (NL_ * NP_);
    const float* vbase = value + (size_t)b * LIN_ * D_ + h * HD_ + d;

    float o = 0.f;
    #pragma unroll
    for (int l = 0; l < NL_; ++l) {
        float rx = refp[l * 2 + 0], ry = refp[l * 2 + 1];
        int wl = levW[l], hl = levH[l];
        const float* vlev = vbase + (size_t)levS[l] * D_;
        #pragma unroll
        for (int p = 0; p < NP_; ++p) {
            float ox = offp[(l * NP_ + p) * 2 + 0];
            float oy = offp[(l * NP_ + p) * 2 + 1];
            float x = rx * wl + ox - 0.5f;   // (ref + off/w)*w - 0.5
            float y = ry * hl + oy - 0.5f;
            float x0f = floorf(x), y0f = floorf(y);
            float fx = x - x0f, fy = y - y0f;
            int x0 = (int)x0f, y0 = (int)y0f;
            float aw = awp[l * NP_ + p];
            float sacc = 0.f;
            #pragma unroll
            for (int dy = 0; dy < 2; ++dy) {
                int  yi = y0 + dy;
                float wy = dy ? fy : 1.f - fy;
                bool vy = (yi >= 0) && (yi < hl);
                int  yc = min(max(yi, 0), hl - 1);
                #pragma unroll
                for (int dx = 0; dx < 2; ++dx) {
                    int  xi = x0 + dx;
                    float wx = dx ? fx : 1.f - fx;
                    bool vx = (xi >= 0) && (xi < wl);
                    int  xc = min(max(xi, 0), wl - 1);
                    float w  = (vx && vy) ? wy * wx : 0.f;
                    float sv = vlev[(size_t)(yc * wl + xc) * D_];
                    sacc += w * sv;
                }
            }
            o += aw * sacc;
        }
    }
    out[gid] = o;
}

// ---------------------------------------------------------------------------
extern "C" void kernel_launch(void* const* d_in, const int* in_sizes, int n_in,
                              void* d_out, int out_size, void* d_ws, size_t ws_size,
                              hipStream_t stream) {
    const float* queries      = (const float*)d_in[0];
    const float* features     = (const float*)d_in[1];
    const float* refpts       = (const float*)d_in[2];
    const float* q_pos        = (const float*)d_in[3];
    const float* in_proj_w    = (const float*)d_in[4];
    const float* in_proj_b    = (const float*)d_in[5];
    const float* out_proj_w   = (const float*)d_in[6];
    const float* out_proj_b   = (const float*)d_in[7];
    const float* value_proj_w = (const float*)d_in[8];
    const float* value_proj_b = (const float*)d_in[9];
    const float* samp_w       = (const float*)d_in[10];
    const float* samp_b       = (const float*)d_in[11];
    const float* attw_w       = (const float*)d_in[12];
    const float* attw_b       = (const float*)d_in[13];
    const float* msout_w      = (const float*)d_in[14];
    const float* msout_b      = (const float*)d_in[15];
    const float* ffn_w1       = (const float*)d_in[16];
    const float* ffn_b1       = (const float*)d_in[17];
    const float* ffn_w2       = (const float*)d_in[18];
    const float* ffn_b2       = (const float*)d_in[19];
    const float* ln1_g        = (const float*)d_in[20];
    const float* ln1_b        = (const float*)d_in[21];
    const float* ln2_g        = (const float*)d_in[22];
    const float* ln2_b        = (const float*)d_in[23];
    const float* ln3_g        = (const float*)d_in[24];
    const float* ln3_b        = (const float*)d_in[25];

    float* ws = (float*)d_ws;
    const size_t NQ = (size_t)B_ * LQ_ * D_;          // 3,686,400
    float* bufA = ws;                                  // qk / O / q2 / ms / ffnpre
    float* bufB = ws + NQ;                             // Q / x1pre / sampoff / x2pre
    float* bufC = ws + 2 * NQ;                         // K / attw_raw / x2
    float* bufD = ws + 3 * NQ;                         // V / attw
    float* bufF = ws + 4 * NQ;                         // x (post-LN1)
    float* VAL  = ws + 5 * NQ;                         // (B, LIN, D)
    float* H1   = VAL + (size_t)B_ * LIN_ * D_;        // (B*LQ, DFFN)

    const int M = B_ * LQ_;      // 14400
    const int MV = B_ * LIN_;    // 348160

    // 1. qk = queries + q_pos
    add_kernel<<<3600, 256, 0, stream>>>(queries, q_pos, bufA, NQ / 4);

    // 2. Q, K (from qk), V (from queries)
    gemm_kernel<<<dim3(4, 225), 256, 0, stream>>>(bufA, in_proj_w,          in_proj_b,       nullptr, bufB, M, 256, 256, 0);
    gemm_kernel<<<dim3(4, 225), 256, 0, stream>>>(bufA, in_proj_w + 65536,  in_proj_b + 256, nullptr, bufC, M, 256, 256, 0);
    gemm_kernel<<<dim3(4, 225), 256, 0, stream>>>(queries, in_proj_w + 131072, in_proj_b + 512, nullptr, bufD, M, 256, 256, 0);

    // 3. attention -> bufA
    attn_kernel<<<dim3(15, NH_, B_), 256, 0, stream>>>(bufB, bufC, bufD, bufA);

    // 4. out-proj + residual(queries) -> bufB; 5. LN1 -> bufF
    gemm_kernel<<<dim3(4, 225), 256, 0, stream>>>(bufA, out_proj_w, out_proj_b, queries, bufB, M, 256, 256, 0);
    ln_kernel<<<3600, 256, 0, stream>>>(bufB, ln1_g, ln1_b, bufF, M);

    // 6. q2 = x + q_pos -> bufA
    add_kernel<<<3600, 256, 0, stream>>>(bufF, q_pos, bufA, NQ / 4);

    // 7. value projection (the big one) -> VAL
    gemm_kernel<<<dim3(4, 5440), 256, 0, stream>>>(features, value_proj_w, value_proj_b, nullptr, VAL, MV, 256, 256, 0);

    // 8. sampling offsets and attention-weight logits
    gemm_kernel<<<dim3(4, 225), 256, 0, stream>>>(bufA, samp_w, samp_b, nullptr, bufB, M, 256, 256, 0);
    gemm_kernel<<<dim3(2, 225), 256, 0, stream>>>(bufA, attw_w, attw_b, nullptr, bufC, M, 128, 256, 0);

    // 9. softmax over 16 -> bufD
    softmax16_kernel<<<450, 256, 0, stream>>>(bufC, bufD, B_ * LQ_ * NH_);

    // 10. deformable sampling -> bufA
    msdeform_kernel<<<14400, 256, 0, stream>>>(VAL, refpts, bufB, bufD, bufA);

    // 11. msout + residual(x) -> bufB; 12. LN2 -> bufC
    gemm_kernel<<<dim3(4, 225), 256, 0, stream>>>(bufA, msout_w, msout_b, bufF, bufB, M, 256, 256, 0);
    ln_kernel<<<3600, 256, 0, stream>>>(bufB, ln2_g, ln2_b, bufC, M);

    // 13. FFN up + ReLU -> H1
    gemm_kernel<<<dim3(32, 225), 256, 0, stream>>>(bufC, ffn_w1, ffn_b1, nullptr, H1, M, 2048, 256, 1);

    // 14. FFN down + residual(x2) -> bufA; 15. LN3 -> d_out
    gemm_kernel<<<dim3(4, 225), 256, 0, stream>>>(H1, ffn_w2, ffn_b2, bufC, bufA, M, 256, 2048, 0);
    ln_kernel<<<3600, 256, 0, stream>>>(bufA, ln3_g, ln3_b, (float*)d_out, M);
}

// Round 2
// 1499.696 us; speedup vs baseline: 1.5072x; 1.5072x over previous
//
#include <hip/hip_runtime.h>
#include <hip/hip_bf16.h>
#include <math.h>

#define B_    16
#define LQ_   900
#define D_    256
#define NH_   8
#define HD_   32
#define NL_   4
#define NP_   4
#define DFFN_ 2048
#define LIN_  21760

typedef __attribute__((ext_vector_type(8))) short bf16x8;
typedef __attribute__((ext_vector_type(4))) float f32x4;

__device__ __forceinline__ short f2bf(float f) {
    unsigned u = __float_as_uint(f);
    u += 0x7fffu + ((u >> 16) & 1u);   // round-to-nearest-even
    return (short)(u >> 16);
}

// ---------------------------------------------------------------------------
// elementwise add (float4)
// ---------------------------------------------------------------------------
__global__ __launch_bounds__(256) void add_kernel(const float* __restrict__ a,
                                                  const float* __restrict__ b,
                                                  float* __restrict__ c,
                                                  size_t n4) {
    size_t i = (size_t)blockIdx.x * blockDim.x + threadIdx.x;
    if (i < n4) {
        float4 x = ((const float4*)a)[i];
        float4 y = ((const float4*)b)[i];
        ((float4*)c)[i] = make_float4(x.x + y.x, x.y + y.y, x.z + y.z, x.w + y.w);
    }
}

// ---------------------------------------------------------------------------
// bf16 MFMA GEMM: C[M,N] = A[M,K] @ W[N,K]^T + bias[N] (+res) (+relu)
// 128x128 tile, BK=32, 256 threads (4 waves, 2x2 of 64x64), fp32 in/out with
// on-the-fly bf16 conversion in staging. LDS rows padded to 40 bf16 (80 B)
// -> (20*row + 4*kg) % 32 bank pattern = 2-way (free, m136).
// Requires: N % 128 == 0, K % 32 == 0.
// ---------------------------------------------------------------------------
#define LDK 40
__global__ __launch_bounds__(256) void gemm_bf16_kernel(const float* __restrict__ A,
                                                        const float* __restrict__ W,
                                                        const float* __restrict__ bias,
                                                        const float* __restrict__ res,
                                                        float* __restrict__ C,
                                                        int M, int N, int K, int relu) {
    __shared__ __align__(16) short As[128 * LDK];
    __shared__ __align__(16) short Bs[128 * LDK];

    const int n0 = blockIdx.x * 128;
    const int m0 = blockIdx.y * 128;
    const int t  = threadIdx.x;

    // staging role: thread t loads row srow, 16 contiguous k (as 4x float4)
    const int srow = t >> 1;
    const int scol = (t & 1) << 4;

    // compute role
    const int lane = t & 63;
    const int lr   = lane & 15;
    const int kg   = lane >> 4;
    const int wid  = t >> 6;
    const int wr   = wid >> 1;   // 0..1
    const int wc   = wid & 1;    // 0..1

    f32x4 acc[4][4] = {};

    const short* pA = &As[(wr * 64 + lr) * LDK + kg * 8];
    const short* pB = &Bs[(wc * 64 + lr) * LDK + kg * 8];

    for (int k0 = 0; k0 < K; k0 += 32) {
        // ---- stage A (guarded) ----
        {
            short tmp[16];
            int gm = m0 + srow;
            if (gm < M) {
                const float* src = A + (size_t)gm * K + k0 + scol;
                #pragma unroll
                for (int q = 0; q < 4; ++q) {
                    float4 v = *(const float4*)(src + q * 4);
                    tmp[q * 4 + 0] = f2bf(v.x);
                    tmp[q * 4 + 1] = f2bf(v.y);
                    tmp[q * 4 + 2] = f2bf(v.z);
                    tmp[q * 4 + 3] = f2bf(v.w);
                }
            } else {
                #pragma unroll
                for (int q = 0; q < 16; ++q) tmp[q] = 0;
            }
            *(bf16x8*)&As[srow * LDK + scol]     = *(bf16x8*)tmp;
            *(bf16x8*)&As[srow * LDK + scol + 8] = *(bf16x8*)(tmp + 8);
        }
        // ---- stage W (N always multiple of 128) ----
        {
            short tmp[16];
            const float* src = W + (size_t)(n0 + srow) * K + k0 + scol;
            #pragma unroll
            for (int q = 0; q < 4; ++q) {
                float4 v = *(const float4*)(src + q * 4);
                tmp[q * 4 + 0] = f2bf(v.x);
                tmp[q * 4 + 1] = f2bf(v.y);
                tmp[q * 4 + 2] = f2bf(v.z);
                tmp[q * 4 + 3] = f2bf(v.w);
            }
            *(bf16x8*)&Bs[srow * LDK + scol]     = *(bf16x8*)tmp;
            *(bf16x8*)&Bs[srow * LDK + scol + 8] = *(bf16x8*)(tmp + 8);
        }
        __syncthreads();

        bf16x8 a[4], b[4];
        #pragma unroll
        for (int i = 0; i < 4; ++i) a[i] = *(const bf16x8*)(pA + i * 16 * LDK);
        #pragma unroll
        for (int j = 0; j < 4; ++j) b[j] = *(const bf16x8*)(pB + j * 16 * LDK);
        #pragma unroll
        for (int i = 0; i < 4; ++i)
            #pragma unroll
            for (int j = 0; j < 4; ++j)
                acc[i][j] = __builtin_amdgcn_mfma_f32_16x16x32_bf16(a[i], b[j], acc[i][j], 0, 0, 0);
        __syncthreads();
    }

    // epilogue: D row = kg*4 + r, col = lr  (m89/m101 verified mapping)
    #pragma unroll
    for (int i = 0; i < 4; ++i) {
        #pragma unroll
        for (int j = 0; j < 4; ++j) {
            const int n = n0 + wc * 64 + j * 16 + lr;
            const float bn = bias[n];
            #pragma unroll
            for (int r = 0; r < 4; ++r) {
                const int m = m0 + wr * 64 + i * 16 + kg * 4 + r;
                if (m < M) {
                    float v = acc[i][j][r] + bn;
                    if (res)  v += res[(size_t)m * N + n];
                    if (relu) v = fmaxf(v, 0.f);
                    C[(size_t)m * N + n] = v;
                }
            }
        }
    }
}

// ---------------------------------------------------------------------------
// flash attention fp32 (unchanged this round)
// ---------------------------------------------------------------------------
__global__ __launch_bounds__(256) void attn_kernel(const float* __restrict__ Qg,
                                                   const float* __restrict__ Kg,
                                                   const float* __restrict__ Vg,
                                                   float* __restrict__ Og) {
    __shared__ float Ks[64][36];
    __shared__ float Vs[64][36];
    __shared__ float Ps[64][65];

    const int qt = blockIdx.x, h = blockIdx.y, b = blockIdx.z;
    const int q0 = qt * 64;
    const int t  = threadIdx.x;
    const int r  = t >> 2;
    const int c4 = t & 3;
    const int d0 = c4 * 8;

    float qreg[32];
    {
        int qg = q0 + r;
        int qsafe = (qg < LQ_) ? qg : 0;
        const float* src = Qg + ((size_t)(b * LQ_ + qsafe)) * D_ + h * HD_;
        #pragma unroll
        for (int d = 0; d < 32; d += 4) {
            float4 v = *(const float4*)(src + d);
            qreg[d] = v.x; qreg[d + 1] = v.y; qreg[d + 2] = v.z; qreg[d + 3] = v.w;
        }
    }

    float m_i = -1e30f, l_i = 0.f;
    float o_[8] = {};
    const float scale = 0.17677669529663687f;

    for (int kt = 0; kt < 15; ++kt) {
        int k0 = kt * 64;
        {
            int kgr = k0 + r;
            if (kgr < LQ_) {
                const float* ksrc = Kg + ((size_t)(b * LQ_ + kgr)) * D_ + h * HD_ + d0;
                const float* vsrc = Vg + ((size_t)(b * LQ_ + kgr)) * D_ + h * HD_ + d0;
                float4 a = *(const float4*)ksrc, a2 = *(const float4*)(ksrc + 4);
                float4 c = *(const float4*)vsrc, c2 = *(const float4*)(vsrc + 4);
                Ks[r][d0 + 0] = a.x;  Ks[r][d0 + 1] = a.y;  Ks[r][d0 + 2] = a.z;  Ks[r][d0 + 3] = a.w;
                Ks[r][d0 + 4] = a2.x; Ks[r][d0 + 5] = a2.y; Ks[r][d0 + 6] = a2.z; Ks[r][d0 + 7] = a2.w;
                Vs[r][d0 + 0] = c.x;  Vs[r][d0 + 1] = c.y;  Vs[r][d0 + 2] = c.z;  Vs[r][d0 + 3] = c.w;
                Vs[r][d0 + 4] = c2.x; Vs[r][d0 + 5] = c2.y; Vs[r][d0 + 6] = c2.z; Vs[r][d0 + 7] = c2.w;
            } else {
                #pragma unroll
                for (int d = 0; d < 8; ++d) { Ks[r][d0 + d] = 0.f; Vs[r][d0 + d] = 0.f; }
            }
        }
        __syncthreads();

        float s[16];
        #pragma unroll
        for (int j = 0; j < 16; ++j) {
            int kidx = c4 + 4 * j;
            const float* kr = &Ks[kidx][0];
            float acc = 0.f;
            #pragma unroll
            for (int d = 0; d < 32; d += 4) {
                float4 kv = *(const float4*)(kr + d);
                acc += qreg[d] * kv.x + qreg[d + 1] * kv.y +
                       qreg[d + 2] * kv.z + qreg[d + 3] * kv.w;
            }
            s[j] = acc;
        }
        float rowmax = -1e30f;
        #pragma unroll
        for (int j = 0; j < 16; ++j) {
            int kidx = c4 + 4 * j;
            s[j] = (k0 + kidx < LQ_) ? s[j] * scale : -1e30f;
            rowmax = fmaxf(rowmax, s[j]);
        }
        rowmax = fmaxf(rowmax, __shfl_xor(rowmax, 1));
        rowmax = fmaxf(rowmax, __shfl_xor(rowmax, 2));
        float newm = fmaxf(m_i, rowmax);
        float corr = expf(m_i - newm);
        float rs = 0.f;
        #pragma unroll
        for (int j = 0; j < 16; ++j) {
            float p = expf(s[j] - newm);
            Ps[r][c4 + 4 * j] = p;
            rs += p;
        }
        rs += __shfl_xor(rs, 1);
        rs += __shfl_xor(rs, 2);
        l_i = l_i * corr + rs;
        m_i = newm;
        #pragma unroll
        for (int d = 0; d < 8; ++d) o_[d] *= corr;
        __syncthreads();

        #pragma unroll 8
        for (int k = 0; k < 64; ++k) {
            float p = Ps[r][k];
            const float* vr = &Vs[k][d0];
            float4 v0 = *(const float4*)vr;
            float4 v1 = *(const float4*)(vr + 4);
            o_[0] += p * v0.x; o_[1] += p * v0.y; o_[2] += p * v0.z; o_[3] += p * v0.w;
            o_[4] += p * v1.x; o_[5] += p * v1.y; o_[6] += p * v1.z; o_[7] += p * v1.w;
        }
        __syncthreads();
    }

    if (q0 + r < LQ_) {
        float inv = 1.f / l_i;
        float* dst = Og + ((size_t)(b * LQ_ + q0 + r)) * D_ + h * HD_ + d0;
        #pragma unroll
        for (int d = 0; d < 8; ++d) dst[d] = o_[d] * inv;
    }
}

// ---------------------------------------------------------------------------
// LayerNorm over D=256; one wave per row, 4 rows per block
// ---------------------------------------------------------------------------
__global__ __launch_bounds__(256) void ln_kernel(const float* __restrict__ X,
                                                 const float* __restrict__ g,
                                                 const float* __restrict__ bb,
                                                 float* __restrict__ Y, int M) {
    int row  = blockIdx.x * 4 + (threadIdx.x >> 6);
    int lane = threadIdx.x & 63;
    if (row >= M) return;
    const float* x = X + (size_t)row * D_;
    float4 v = *(const float4*)(x + lane * 4);
    float s = v.x + v.y + v.z + v.w;
    #pragma unroll
    for (int o = 32; o >= 1; o >>= 1) s += __shfl_xor(s, o);
    float mean = s * (1.f / D_);
    float dx0 = v.x - mean, dx1 = v.y - mean, dx2 = v.z - mean, dx3 = v.w - mean;
    float ss = dx0 * dx0 + dx1 * dx1 + dx2 * dx2 + dx3 * dx3;
    #pragma unroll
    for (int o = 32; o >= 1; o >>= 1) ss += __shfl_xor(ss, o);
    float rstd = rsqrtf(ss * (1.f / D_) + 1e-5f);
    float4 gv = *(const float4*)(g + lane * 4);
    float4 bv = *(const float4*)(bb + lane * 4);
    float4 out;
    out.x = dx0 * rstd * gv.x + bv.x;
    out.y = dx1 * rstd * gv.y + bv.y;
    out.z = dx2 * rstd * gv.z + bv.z;
    out.w = dx3 * rstd * gv.w + bv.w;
    *(float4*)(Y + (size_t)row * D_ + lane * 4) = out;
}

// ---------------------------------------------------------------------------
// softmax over 16 contiguous elems per row (B*LQ*NH rows)
// ---------------------------------------------------------------------------
__global__ __launch_bounds__(256) void softmax16_kernel(const float* __restrict__ X,
                                                        float* __restrict__ Y,
                                                        int rows) {
    int r = blockIdx.x * blockDim.x + threadIdx.x;
    if (r >= rows) return;
    const float* x = X + (size_t)r * 16;
    float m = -1e30f;
    #pragma unroll
    for (int i = 0; i < 16; ++i) m = fmaxf(m, x[i]);
    float e[16], s = 0.f;
    #pragma unroll
    for (int i = 0; i < 16; ++i) { e[i] = expf(x[i] - m); s += e[i]; }
    float inv = 1.f / s;
    float* y = Y + (size_t)r * 16;
    #pragma unroll
    for (int i = 0; i < 16; ++i) y[i] = e[i] * inv;
}

// ---------------------------------------------------------------------------
// multi-scale deformable sampling: one thread per (b,q,h,d)
// ---------------------------------------------------------------------------
__global__ __launch_bounds__(256) void msdeform_kernel(const float* __restrict__ value,
                                                       const float* __restrict__ ref,
                                                       const float* __restrict__ off,
                                                       const float* __restrict__ attw,
                                                       float* __restrict__ out) {
    const int levH[4] = {128, 64, 32, 16};
    const int levW[4] = {128, 64, 32, 16};
    const int levS[4] = {0, 16384, 20480, 21504};

    int gid = blockIdx.x * 256 + threadIdx.x;
    int d   = gid & (HD_ - 1);
    int bqh = gid >> 5;
    int h   = bqh & (NH_ - 1);
    int bq  = bqh >> 3;
    int b   = bq / LQ_;

    const float* refp = ref + (size_t)bq * NL_ * 2;
    const float* offp = off + (size_t)bq * (NH_ * NL_ * NP_ * 2) + h * (NL_ * NP_ * 2);
    const float* awp  = attw + (size_t)bq * (NH_ * NL_ * NP_) + h * (NL_ * NP_);
    const float* vbase = value + (size_t)b * LIN_ * D_ + h * HD_ + d;

    float o = 0.f;
    #pragma unroll
    for (int l = 0; l < NL_; ++l) {
        float rx = refp[l * 2 + 0], ry = refp[l * 2 + 1];
        int wl = levW[l], hl = levH[l];
        const float* vlev = vbase + (size_t)levS[l] * D_;
        #pragma unroll
        for (int p = 0; p < NP_; ++p) {
            float ox = offp[(l * NP_ + p) * 2 + 0];
            float oy = offp[(l * NP_ + p) * 2 + 1];
            float x = rx * wl + ox - 0.5f;
            float y = ry * hl + oy - 0.5f;
            float x0f = floorf(x), y0f = floorf(y);
            float fx = x - x0f, fy = y - y0f;
            int x0 = (int)x0f, y0 = (int)y0f;
            float aw = awp[l * NP_ + p];
            float sacc = 0.f;
            #pragma unroll
            for (int dy = 0; dy < 2; ++dy) {
                int  yi = y0 + dy;
                float wy = dy ? fy : 1.f - fy;
                bool vy = (yi >= 0) && (yi < hl);
                int  yc = min(max(yi, 0), hl - 1);
                #pragma unroll
                for (int dx = 0; dx < 2; ++dx) {
                    int  xi = x0 + dx;
                    float wx = dx ? fx : 1.f - fx;
                    bool vx = (xi >= 0) && (xi < wl);
                    int  xc = min(max(xi, 0), wl - 1);
                    float w  = (vx && vy) ? wy * wx : 0.f;
                    float sv = vlev[(size_t)(yc * wl + xc) * D_];
                    sacc += w * sv;
                }
            }
            o += aw * sacc;
        }
    }
    out[gid] = o;
}

// ---------------------------------------------------------------------------
extern "C" void kernel_launch(void* const* d_in, const int* in_sizes, int n_in,
                              void* d_out, int out_size, void* d_ws, size_t ws_size,
                              hipStream_t stream) {
    const float* queries      = (const float*)d_in[0];
    const float* features     = (const float*)d_in[1];
    const float* refpts       = (const float*)d_in[2];
    const float* q_pos        = (const float*)d_in[3];
    const float* in_proj_w    = (const float*)d_in[4];
    const float* in_proj_b    = (const float*)d_in[5];
    const float* out_proj_w   = (const float*)d_in[6];
    const float* out_proj_b   = (const float*)d_in[7];
    const float* value_proj_w = (const float*)d_in[8];
    const float* value_proj_b = (const float*)d_in[9];
    const float* samp_w       = (const float*)d_in[10];
    const float* samp_b       = (const float*)d_in[11];
    const float* attw_w       = (const float*)d_in[12];
    const float* attw_b       = (const float*)d_in[13];
    const float* msout_w      = (const float*)d_in[14];
    const float* msout_b      = (const float*)d_in[15];
    const float* ffn_w1       = (const float*)d_in[16];
    const float* ffn_b1       = (const float*)d_in[17];
    const float* ffn_w2       = (const float*)d_in[18];
    const float* ffn_b2       = (const float*)d_in[19];
    const float* ln1_g        = (const float*)d_in[20];
    const float* ln1_b        = (const float*)d_in[21];
    const float* ln2_g        = (const float*)d_in[22];
    const float* ln2_b        = (const float*)d_in[23];
    const float* ln3_g        = (const float*)d_in[24];
    const float* ln3_b        = (const float*)d_in[25];

    float* ws = (float*)d_ws;
    const size_t NQ = (size_t)B_ * LQ_ * D_;          // 3,686,400
    float* bufA = ws;
    float* bufB = ws + NQ;
    float* bufC = ws + 2 * NQ;
    float* bufD = ws + 3 * NQ;
    float* bufF = ws + 4 * NQ;
    float* VAL  = ws + 5 * NQ;                         // (B, LIN, D)
    float* H1   = VAL + (size_t)B_ * LIN_ * D_;        // (B*LQ, DFFN)

    const int M  = B_ * LQ_;      // 14400
    const int MV = B_ * LIN_;     // 348160
    const int GY = (M + 127) / 128;   // 113

    // 1. qk = queries + q_pos
    add_kernel<<<3600, 256, 0, stream>>>(queries, q_pos, bufA, NQ / 4);

    // 2. Q, K (from qk), V (from queries)
    gemm_bf16_kernel<<<dim3(2, GY), 256, 0, stream>>>(bufA, in_proj_w,          in_proj_b,       nullptr, bufB, M, 256, 256, 0);
    gemm_bf16_kernel<<<dim3(2, GY), 256, 0, stream>>>(bufA, in_proj_w + 65536,  in_proj_b + 256, nullptr, bufC, M, 256, 256, 0);
    gemm_bf16_kernel<<<dim3(2, GY), 256, 0, stream>>>(queries, in_proj_w + 131072, in_proj_b + 512, nullptr, bufD, M, 256, 256, 0);

    // 3. attention -> bufA
    attn_kernel<<<dim3(15, NH_, B_), 256, 0, stream>>>(bufB, bufC, bufD, bufA);

    // 4. out-proj + residual(queries) -> bufB; 5. LN1 -> bufF
    gemm_bf16_kernel<<<dim3(2, GY), 256, 0, stream>>>(bufA, out_proj_w, out_proj_b, queries, bufB, M, 256, 256, 0);
    ln_kernel<<<3600, 256, 0, stream>>>(bufB, ln1_g, ln1_b, bufF, M);

    // 6. q2 = x + q_pos -> bufA
    add_kernel<<<3600, 256, 0, stream>>>(bufF, q_pos, bufA, NQ / 4);

    // 7. value projection (the big one) -> VAL
    gemm_bf16_kernel<<<dim3(2, MV / 128), 256, 0, stream>>>(features, value_proj_w, value_proj_b, nullptr, VAL, MV, 256, 256, 0);

    // 8. sampling offsets and attention-weight logits
    gemm_bf16_kernel<<<dim3(2, GY), 256, 0, stream>>>(bufA, samp_w, samp_b, nullptr, bufB, M, 256, 256, 0);
    gemm_bf16_kernel<<<dim3(1, GY), 256, 0, stream>>>(bufA, attw_w, attw_b, nullptr, bufC, M, 128, 256, 0);

    // 9. softmax over 16 -> bufD
    softmax16_kernel<<<450, 256, 0, stream>>>(bufC, bufD, B_ * LQ_ * NH_);

    // 10. deformable sampling -> bufA
    msdeform_kernel<<<14400, 256, 0, stream>>>(VAL, refpts, bufB, bufD, bufA);

    // 11. msout + residual(x) -> bufB; 12. LN2 -> bufC
    gemm_bf16_kernel<<<dim3(2, GY), 256, 0, stream>>>(bufA, msout_w, msout_b, bufF, bufB, M, 256, 256, 0);
    ln_kernel<<<3600, 256, 0, stream>>>(bufB, ln2_g, ln2_b, bufC, M);

    // 13. FFN up + ReLU -> H1
    gemm_bf16_kernel<<<dim3(16, GY), 256, 0, stream>>>(bufC, ffn_w1, ffn_b1, nullptr, H1, M, 2048, 256, 1);

    // 14. FFN down + residual(x2) -> bufA; 15. LN3 -> d_out
    gemm_bf16_kernel<<<dim3(2, GY), 256, 0, stream>>>(H1, ffn_w2, ffn_b2, bufC, bufA, M, 256, 2048, 0);
    ln_kernel<<<3600, 256, 0, stream>>>(bufA, ln3_g, ln3_b, (float*)d_out, M);
}

// Round 5
// 1195.601 us; speedup vs baseline: 1.8905x; 1.2543x over previous
//
#include <hip/hip_runtime.h>
#include <hip/hip_bf16.h>
#include <math.h>

#define B_    16
#define LQ_   900
#define D_    256
#define NH_   8
#define HD_   32
#define NL_   4
#define NP_   4
#define DFFN_ 2048
#define LIN_  21760

typedef unsigned short u16;
typedef __attribute__((ext_vector_type(8))) short bf16x8;
typedef __attribute__((ext_vector_type(4))) float f32x4;

__device__ __forceinline__ short f2bf(float f) {
    unsigned u = __float_as_uint(f);
    u += 0x7fffu + ((u >> 16) & 1u);   // RNE
    return (short)(u >> 16);
}
__device__ __forceinline__ float bf2f(u16 u) {
    return __uint_as_float(((unsigned)u) << 16);
}

// ---------------------------------------------------------------------------
// elementwise add (float4)
// ---------------------------------------------------------------------------
__global__ __launch_bounds__(256) void add_kernel(const float* __restrict__ a,
                                                  const float* __restrict__ b,
                                                  float* __restrict__ c,
                                                  size_t n4) {
    size_t i = (size_t)blockIdx.x * blockDim.x + threadIdx.x;
    if (i < n4) {
        float4 x = ((const float4*)a)[i];
        float4 y = ((const float4*)b)[i];
        ((float4*)c)[i] = make_float4(x.x + y.x, x.y + y.y, x.z + y.z, x.w + y.w);
    }
}

// ---------------------------------------------------------------------------
// bf16 MFMA GEMM, templated on A-input type and C-output type.
// C[M,N] = A[M,K] @ W[N,K]^T + bias[N] (+res f32) (+relu)
// 128x128 tile, BK=32, 256 threads (4 waves 2x2). W always f32.
// ---------------------------------------------------------------------------
#define LDK 40
template <typename TA, typename TC>
__global__ __launch_bounds__(256) void gemm_t_kernel(const TA* __restrict__ A,
                                                     const float* __restrict__ W,
                                                     const float* __restrict__ bias,
                                                     const float* __restrict__ res,
                                                     TC* __restrict__ C,
                                                     int M, int N, int K, int relu) {
    __shared__ __align__(16) short As[128 * LDK];
    __shared__ __align__(16) short Bs[128 * LDK];

    const int n0 = blockIdx.x * 128;
    const int m0 = blockIdx.y * 128;
    const int t  = threadIdx.x;

    const int srow = t >> 1;
    const int scol = (t & 1) << 4;

    const int lane = t & 63;
    const int lr   = lane & 15;
    const int kg   = lane >> 4;
    const int wid  = t >> 6;
    const int wr   = wid >> 1;
    const int wc   = wid & 1;

    f32x4 acc[4][4] = {};

    const short* pA = &As[(wr * 64 + lr) * LDK + kg * 8];
    const short* pB = &Bs[(wc * 64 + lr) * LDK + kg * 8];

    for (int k0 = 0; k0 < K; k0 += 32) {
        // ---- stage A ----
        {
            int gm = m0 + srow;
            if constexpr (sizeof(TA) == 4) {
                short tmp[16];
                if (gm < M) {
                    const float* src = (const float*)A + (size_t)gm * K + k0 + scol;
                    #pragma unroll
                    for (int q = 0; q < 4; ++q) {
                        float4 v = *(const float4*)(src + q * 4);
                        tmp[q * 4 + 0] = f2bf(v.x);
                        tmp[q * 4 + 1] = f2bf(v.y);
                        tmp[q * 4 + 2] = f2bf(v.z);
                        tmp[q * 4 + 3] = f2bf(v.w);
                    }
                } else {
                    #pragma unroll
                    for (int q = 0; q < 16; ++q) tmp[q] = 0;
                }
                *(bf16x8*)&As[srow * LDK + scol]     = *(bf16x8*)tmp;
                *(bf16x8*)&As[srow * LDK + scol + 8] = *(bf16x8*)(tmp + 8);
            } else {
                bf16x8 v0, v1;
                if (gm < M) {
                    const u16* src = (const u16*)A + (size_t)gm * K + k0 + scol;
                    v0 = *(const bf16x8*)src;
                    v1 = *(const bf16x8*)(src + 8);
                } else {
                    #pragma unroll
                    for (int q = 0; q < 8; ++q) { v0[q] = 0; v1[q] = 0; }
                }
                *(bf16x8*)&As[srow * LDK + scol]     = v0;
                *(bf16x8*)&As[srow * LDK + scol + 8] = v1;
            }
        }
        // ---- stage W (f32, N multiple of 128) ----
        {
            short tmp[16];
            const float* src = W + (size_t)(n0 + srow) * K + k0 + scol;
            #pragma unroll
            for (int q = 0; q < 4; ++q) {
                float4 v = *(const float4*)(src + q * 4);
                tmp[q * 4 + 0] = f2bf(v.x);
                tmp[q * 4 + 1] = f2bf(v.y);
                tmp[q * 4 + 2] = f2bf(v.z);
                tmp[q * 4 + 3] = f2bf(v.w);
            }
            *(bf16x8*)&Bs[srow * LDK + scol]     = *(bf16x8*)tmp;
            *(bf16x8*)&Bs[srow * LDK + scol + 8] = *(bf16x8*)(tmp + 8);
        }
        __syncthreads();

        bf16x8 a[4], b[4];
        #pragma unroll
        for (int i = 0; i < 4; ++i) a[i] = *(const bf16x8*)(pA + i * 16 * LDK);
        #pragma unroll
        for (int j = 0; j < 4; ++j) b[j] = *(const bf16x8*)(pB + j * 16 * LDK);
        #pragma unroll
        for (int i = 0; i < 4; ++i)
            #pragma unroll
            for (int j = 0; j < 4; ++j)
                acc[i][j] = __builtin_amdgcn_mfma_f32_16x16x32_bf16(a[i], b[j], acc[i][j], 0, 0, 0);
        __syncthreads();
    }

    #pragma unroll
    for (int i = 0; i < 4; ++i) {
        #pragma unroll
        for (int j = 0; j < 4; ++j) {
            const int n = n0 + wc * 64 + j * 16 + lr;
            const float bn = bias[n];
            #pragma unroll
            for (int r = 0; r < 4; ++r) {
                const int m = m0 + wr * 64 + i * 16 + kg * 4 + r;
                if (m < M) {
                    float v = acc[i][j][r] + bn;
                    if (res)  v += res[(size_t)m * N + n];
                    if (relu) v = fmaxf(v, 0.f);
                    if constexpr (sizeof(TC) == 4) C[(size_t)m * N + n] = v;
                    else                           C[(size_t)m * N + n] = (TC)(u16)f2bf(v);
                }
            }
        }
    }
}

// ---------------------------------------------------------------------------
// MFMA flash attention, bf16 in/out, fp32 softmax.
// grid (15, NH, B); block 256 = 4 waves; wave wq owns q rows qt*64+wq*16+(0..15).
// Swapped QK^T: S^T = mfma(K, Q) -> stats lane-local at q = lane&15.
// P packed bf16 -> per-wave LDS; PV: O = mfma(P, V-gather).
// ---------------------------------------------------------------------------
#define LDA2 40   // shorts per K/V LDS row (80 B: 16B-aligned, 2-way banks)
#define LDP  72   // shorts per P LDS row (144 B: 16B-aligned, 2-way banks)
__global__ __launch_bounds__(256) void attn_mfma_kernel(const u16* __restrict__ Qg,
                                                        const u16* __restrict__ Kg,
                                                        const u16* __restrict__ Vg,
                                                        u16* __restrict__ Og) {
    __shared__ __align__(16) u16 Ks[64 * LDA2];
    __shared__ __align__(16) u16 Vs[64 * LDA2];
    __shared__ __align__(16) u16 Ps[4][16 * LDP];

    const int qt = blockIdx.x, h = blockIdx.y, b = blockIdx.z;
    const int t  = threadIdx.x;
    const int wq = t >> 6;
    const int lane = t & 63;
    const int l15  = lane & 15;
    const int g    = lane >> 4;
    const int q0   = qt * 64;

    const int srow = t >> 2;
    const int sd   = (t & 3) * 8;

    int qrow = q0 + wq * 16 + l15;
    if (qrow > LQ_ - 1) qrow = LQ_ - 1;
    const bf16x8 qfrag = *(const bf16x8*)(Qg + ((size_t)(b * LQ_) + qrow) * D_ + h * HD_ + g * 8);

    float m_i = -1e30f, l_i = 0.f;
    f32x4 o_acc[2] = {};
    const float scale = 0.17677669529663687f;  // 1/sqrt(32)

    for (int k0 = 0; k0 < 960; k0 += 64) {
        {
            int kr = k0 + srow;
            bf16x8 kv, vv;
            if (kr < LQ_) {
                kv = *(const bf16x8*)(Kg + ((size_t)(b * LQ_) + kr) * D_ + h * HD_ + sd);
                vv = *(const bf16x8*)(Vg + ((size_t)(b * LQ_) + kr) * D_ + h * HD_ + sd);
            } else {
                #pragma unroll
                for (int j = 0; j < 8; ++j) { kv[j] = 0; vv[j] = 0; }
            }
            *(bf16x8*)&Ks[srow * LDA2 + sd] = kv;
            *(bf16x8*)&Vs[srow * LDA2 + sd] = vv;
        }
        __syncthreads();

        float p[4][4];
        float tmax = -1e30f;
        #pragma unroll
        for (int kt = 0; kt < 4; ++kt) {
            bf16x8 af = *(const bf16x8*)&Ks[(kt * 16 + l15) * LDA2 + g * 8];
            f32x4 c = {0.f, 0.f, 0.f, 0.f};
            c = __builtin_amdgcn_mfma_f32_16x16x32_bf16(af, qfrag, c, 0, 0, 0);
            #pragma unroll
            for (int r = 0; r < 4; ++r) {
                int kglob = k0 + kt * 16 + g * 4 + r;
                float s = (kglob < LQ_) ? c[r] * scale : -1e30f;
                p[kt][r] = s;
                tmax = fmaxf(tmax, s);
            }
        }
        tmax = fmaxf(tmax, __shfl_xor(tmax, 16));
        tmax = fmaxf(tmax, __shfl_xor(tmax, 32));
        float newm = fmaxf(m_i, tmax);
        float corr = __expf(m_i - newm);
        float rs = 0.f;
        #pragma unroll
        for (int kt = 0; kt < 4; ++kt) {
            #pragma unroll
            for (int r = 0; r < 4; ++r) {
                float e = __expf(p[kt][r] - newm);
                p[kt][r] = e;
                rs += e;
            }
            ushort4 pk;
            pk.x = (u16)f2bf(p[kt][0]);
            pk.y = (u16)f2bf(p[kt][1]);
            pk.z = (u16)f2bf(p[kt][2]);
            pk.w = (u16)f2bf(p[kt][3]);
            *(ushort4*)&Ps[wq][l15 * LDP + kt * 16 + g * 4] = pk;
        }
        rs += __shfl_xor(rs, 16);
        rs += __shfl_xor(rs, 32);
        l_i = l_i * corr + rs;
        m_i = newm;

        #pragma unroll
        for (int r = 0; r < 4; ++r) {
            float cq = __shfl(corr, g * 4 + r);
            o_acc[0][r] *= cq;
            o_acc[1][r] *= cq;
        }

        #pragma unroll
        for (int c = 0; c < 2; ++c) {
            bf16x8 pa = *(const bf16x8*)&Ps[wq][l15 * LDP + c * 32 + g * 8];
            #pragma unroll
            for (int nt = 0; nt < 2; ++nt) {
                short vv[8];
                #pragma unroll
                for (int j = 0; j < 8; ++j)
                    vv[j] = (short)Vs[(c * 32 + g * 8 + j) * LDA2 + nt * 16 + l15];
                o_acc[nt] = __builtin_amdgcn_mfma_f32_16x16x32_bf16(pa, *(bf16x8*)vv, o_acc[nt], 0, 0, 0);
            }
        }
        __syncthreads();
    }

    float il = 1.f / l_i;
    #pragma unroll
    for (int r = 0; r < 4; ++r) {
        float ilq = __shfl(il, g * 4 + r);
        int q = q0 + wq * 16 + g * 4 + r;
        if (q < LQ_) {
            u16* dst = Og + ((size_t)(b * LQ_) + q) * D_ + h * HD_ + l15;
            dst[0]  = (u16)f2bf(o_acc[0][r] * ilq);
            dst[16] = (u16)f2bf(o_acc[1][r] * ilq);
        }
    }
}

// ---------------------------------------------------------------------------
// LayerNorm over D=256; one wave per row, 4 rows per block
// ---------------------------------------------------------------------------
__global__ __launch_bounds__(256) void ln_kernel(const float* __restrict__ X,
                                                 const float* __restrict__ g,
                                                 const float* __restrict__ bb,
                                                 float* __restrict__ Y, int M) {
    int row  = blockIdx.x * 4 + (threadIdx.x >> 6);
    int lane = threadIdx.x & 63;
    if (row >= M) return;
    const float* x = X + (size_t)row * D_;
    float4 v = *(const float4*)(x + lane * 4);
    float s = v.x + v.y + v.z + v.w;
    #pragma unroll
    for (int o = 32; o >= 1; o >>= 1) s += __shfl_xor(s, o);
    float mean = s * (1.f / D_);
    float dx0 = v.x - mean, dx1 = v.y - mean, dx2 = v.z - mean, dx3 = v.w - mean;
    float ss = dx0 * dx0 + dx1 * dx1 + dx2 * dx2 + dx3 * dx3;
    #pragma unroll
    for (int o = 32; o >= 1; o >>= 1) ss += __shfl_xor(ss, o);
    float rstd = rsqrtf(ss * (1.f / D_) + 1e-5f);
    float4 gv = *(const float4*)(g + lane * 4);
    float4 bv = *(const float4*)(bb + lane * 4);
    float4 out;
    out.x = dx0 * rstd * gv.x + bv.x;
    out.y = dx1 * rstd * gv.y + bv.y;
    out.z = dx2 * rstd * gv.z + bv.z;
    out.w = dx3 * rstd * gv.w + bv.w;
    *(float4*)(Y + (size_t)row * D_ + lane * 4) = out;
}

// ---------------------------------------------------------------------------
// softmax over 16 contiguous elems per row
// ---------------------------------------------------------------------------
__global__ __launch_bounds__(256) void softmax16_kernel(const float* __restrict__ X,
                                                        float* __restrict__ Y,
                                                        int rows) {
    int r = blockIdx.x * blockDim.x + threadIdx.x;
    if (r >= rows) return;
    const float* x = X + (size_t)r * 16;
    float m = -1e30f;
    #pragma unroll
    for (int i = 0; i < 16; ++i) m = fmaxf(m, x[i]);
    float e[16], s = 0.f;
    #pragma unroll
    for (int i = 0; i < 16; ++i) { e[i] = expf(x[i] - m); s += e[i]; }
    float inv = 1.f / s;
    float* y = Y + (size_t)r * 16;
    #pragma unroll
    for (int i = 0; i < 16; ++i) y[i] = e[i] * inv;
}

// ---------------------------------------------------------------------------
// multi-scale deformable sampling: value is bf16. one thread per (b,q,h,d)
// ---------------------------------------------------------------------------
__global__ __launch_bounds__(256) void msdeform_kernel(const u16* __restrict__ value,
                                                       const float* __restrict__ ref,
                                                       const float* __restrict__ off,
                                                       const float* __restrict__ attw,
                                                       float* __restrict__ out) {
    const int levH[4] = {128, 64, 32, 16};
    const int levW[4] = {128, 64, 32, 16};
    const int levS[4] = {0, 16384, 20480, 21504};

    int gid = blockIdx.x * 256 + threadIdx.x;
    int d   = gid & (HD_ - 1);
    int bqh = gid >> 5;
    int h   = bqh & (NH_ - 1);
    int bq  = bqh >> 3;
    int b   = bq / LQ_;

    const float* refp = ref + (size_t)bq * NL_ * 2;
    const float* offp = off + (size_t)bq * (NH_ * NL_ * NP_ * 2) + h * (NL_ * NP_ * 2);
    const float* awp  = attw + (size_t)bq * (NH_ * NL_ * NP_) + h * (NL_ * NP_);
    const u16* vbase  = value + (size_t)b * LIN_ * D_ + h * HD_ + d;

    float o = 0.f;
    #pragma unroll
    for (int l = 0; l < NL_; ++l) {
        float rx = refp[l * 2 + 0], ry = refp[l * 2 + 1];
        int wl = levW[l], hl = levH[l];
        const u16* vlev = vbase + (size_t)levS[l] * D_;
        #pragma unroll
        for (int p = 0; p < NP_; ++p) {
            float ox = offp[(l * NP_ + p) * 2 + 0];
            float oy = offp[(l * NP_ + p) * 2 + 1];
            float x = rx * wl + ox - 0.5f;
            float y = ry * hl + oy - 0.5f;
            float x0f = floorf(x), y0f = floorf(y);
            float fx = x - x0f, fy = y - y0f;
            int x0 = (int)x0f, y0 = (int)y0f;
            float aw = awp[l * NP_ + p];
            float sacc = 0.f;
            #pragma unroll
            for (int dy = 0; dy < 2; ++dy) {
                int  yi = y0 + dy;
                float wy = dy ? fy : 1.f - fy;
                bool vy = (yi >= 0) && (yi < hl);
                int  yc = min(max(yi, 0), hl - 1);
                #pragma unroll
                for (int dx = 0; dx < 2; ++dx) {
                    int  xi = x0 + dx;
                    float wx = dx ? fx : 1.f - fx;
                    bool vx = (xi >= 0) && (xi < wl);
                    int  xc = min(max(xi, 0), wl - 1);
                    float w  = (vx && vy) ? wy * wx : 0.f;
                    float sv = bf2f(vlev[(size_t)(yc * wl + xc) * D_]);
                    sacc += w * sv;
                }
            }
            o += aw * sacc;
        }
    }
    out[gid] = o;
}

// ---------------------------------------------------------------------------
extern "C" void kernel_launch(void* const* d_in, const int* in_sizes, int n_in,
                              void* d_out, int out_size, void* d_ws, size_t ws_size,
                              hipStream_t stream) {
    const float* queries      = (const float*)d_in[0];
    const float* features     = (const float*)d_in[1];
    const float* refpts       = (const float*)d_in[2];
    const float* q_pos        = (const float*)d_in[3];
    const float* in_proj_w    = (const float*)d_in[4];
    const float* in_proj_b    = (const float*)d_in[5];
    const float* out_proj_w   = (const float*)d_in[6];
    const float* out_proj_b   = (const float*)d_in[7];
    const float* value_proj_w = (const float*)d_in[8];
    const float* value_proj_b = (const float*)d_in[9];
    const float* samp_w       = (const float*)d_in[10];
    const float* samp_b       = (const float*)d_in[11];
    const float* attw_w       = (const float*)d_in[12];
    const float* attw_b       = (const float*)d_in[13];
    const float* msout_w      = (const float*)d_in[14];
    const float* msout_b      = (const float*)d_in[15];
    const float* ffn_w1       = (const float*)d_in[16];
    const float* ffn_b1       = (const float*)d_in[17];
    const float* ffn_w2       = (const float*)d_in[18];
    const float* ffn_b2       = (const float*)d_in[19];
    const float* ln1_g        = (const float*)d_in[20];
    const float* ln1_b        = (const float*)d_in[21];
    const float* ln2_g        = (const float*)d_in[22];
    const float* ln2_b        = (const float*)d_in[23];
    const float* ln3_g        = (const float*)d_in[24];
    const float* ln3_b        = (const float*)d_in[25];

    float* ws = (float*)d_ws;
    const size_t NQ = (size_t)B_ * LQ_ * D_;          // 3,686,400
    float* bufA = ws;
    float* bufB = ws + NQ;
    float* bufC = ws + 2 * NQ;
    float* bufD = ws + 3 * NQ;
    float* bufF = ws + 4 * NQ;
    u16* VALb = (u16*)(ws + 5 * NQ);                  // (B, LIN, D) bf16
    u16* H1b  = VALb + (size_t)B_ * LIN_ * D_;        // (B*LQ, DFFN) bf16
    u16* Qb   = H1b + (size_t)B_ * LQ_ * DFFN_;
    u16* Kb   = Qb + NQ;
    u16* Vb   = Kb + NQ;
    u16* Ob   = Vb + NQ;

    const int M  = B_ * LQ_;      // 14400
    const int MV = B_ * LIN_;     // 348160
    const int GY = (M + 127) / 128;   // 113

    // 1. qk = queries + q_pos
    add_kernel<<<3600, 256, 0, stream>>>(queries, q_pos, bufA, NQ / 4);

    // 2. Q, K (from qk), V (from queries) -> bf16
    gemm_t_kernel<float, u16><<<dim3(2, GY), 256, 0, stream>>>(bufA, in_proj_w,          in_proj_b,       nullptr, Qb, M, 256, 256, 0);
    gemm_t_kernel<float, u16><<<dim3(2, GY), 256, 0, stream>>>(bufA, in_proj_w + 65536,  in_proj_b + 256, nullptr, Kb, M, 256, 256, 0);
    gemm_t_kernel<float, u16><<<dim3(2, GY), 256, 0, stream>>>(queries, in_proj_w + 131072, in_proj_b + 512, nullptr, Vb, M, 256, 256, 0);

    // 3. MFMA flash attention -> Ob (bf16)
    attn_mfma_kernel<<<dim3(15, NH_, B_), 256, 0, stream>>>(Qb, Kb, Vb, Ob);

    // 4. out-proj + residual(queries) -> bufB; 5. LN1 -> bufF
    gemm_t_kernel<u16, float><<<dim3(2, GY), 256, 0, stream>>>(Ob, out_proj_w, out_proj_b, queries, bufB, M, 256, 256, 0);
    ln_kernel<<<3600, 256, 0, stream>>>(bufB, ln1_g, ln1_b, bufF, M);

    // 6. q2 = x + q_pos -> bufA
    add_kernel<<<3600, 256, 0, stream>>>(bufF, q_pos, bufA, NQ / 4);

    // 7. value projection -> VALb (bf16)
    gemm_t_kernel<float, u16><<<dim3(2, MV / 128), 256, 0, stream>>>(features, value_proj_w, value_proj_b, nullptr, VALb, MV, 256, 256, 0);

    // 8. sampling offsets and attention-weight logits (f32)
    gemm_t_kernel<float, float><<<dim3(2, GY), 256, 0, stream>>>(bufA, samp_w, samp_b, nullptr, bufB, M, 256, 256, 0);
    gemm_t_kernel<float, float><<<dim3(1, GY), 256, 0, stream>>>(bufA, attw_w, attw_b, nullptr, bufC, M, 128, 256, 0);

    // 9. softmax over 16 -> bufD
    softmax16_kernel<<<450, 256, 0, stream>>>(bufC, bufD, B_ * LQ_ * NH_);

    // 10. deformable sampling (bf16 value) -> bufA
    msdeform_kernel<<<14400, 256, 0, stream>>>(VALb, refpts, bufB, bufD, bufA);

    // 11. msout + residual(x) -> bufB; 12. LN2 -> bufC
    gemm_t_kernel<float, float><<<dim3(2, GY), 256, 0, stream>>>(bufA, msout_w, msout_b, bufF, bufB, M, 256, 256, 0);
    ln_kernel<<<3600, 256, 0, stream>>>(bufB, ln2_g, ln2_b, bufC, M);

    // 13. FFN up + ReLU -> H1b (bf16)
    gemm_t_kernel<float, u16><<<dim3(16, GY), 256, 0, stream>>>(bufC, ffn_w1, ffn_b1, nullptr, H1b, M, 2048, 256, 1);

    // 14. FFN down (bf16 A) + residual(x2) -> bufA; 15. LN3 -> d_out
    gemm_t_kernel<u16, float><<<dim3(2, GY), 256, 0, stream>>>(H1b, ffn_w2, ffn_b2, bufC, bufA, M, 256, 2048, 0);
    ln_kernel<<<3600, 256, 0, stream>>>(bufA, ln3_g, ln3_b, (float*)d_out, M);
}

// Round 6
// 1055.300 us; speedup vs baseline: 2.1419x; 1.1329x over previous
//
#include <hip/hip_runtime.h>
#include <hip/hip_bf16.h>
#include <math.h>

#define B_    16
#define LQ_   900
#define D_    256
#define NH_   8
#define HD_   32
#define NL_   4
#define NP_   4
#define DFFN_ 2048
#define LIN_  21760

typedef unsigned short u16;
typedef __attribute__((ext_vector_type(8))) short bf16x8;
typedef __attribute__((ext_vector_type(4))) float f32x4;

__device__ __forceinline__ short f2bf(float f) {
    unsigned u = __float_as_uint(f);
    u += 0x7fffu + ((u >> 16) & 1u);   // RNE
    return (short)(u >> 16);
}
__device__ __forceinline__ float bf2f(u16 u) {
    return __uint_as_float(((unsigned)u) << 16);
}

// ---------------------------------------------------------------------------
// weight prep: convert all fp32 weight matrices to bf16 into one Wb region
// ---------------------------------------------------------------------------
#define WOFF_INPROJ  0
#define WOFF_OUTPROJ 196608
#define WOFF_VALPROJ 262144
#define WOFF_SAMP    327680
#define WOFF_ATTW    393216
#define WOFF_MSOUT   425984
#define WOFF_FFN1    491520
#define WOFF_FFN2    1015808
#define WTOTAL       1540096

__global__ __launch_bounds__(256) void wprep_kernel(const float* __restrict__ s0,  // in_proj
                                                    const float* __restrict__ s1,  // out_proj
                                                    const float* __restrict__ s2,  // val_proj
                                                    const float* __restrict__ s3,  // samp
                                                    const float* __restrict__ s4,  // attw
                                                    const float* __restrict__ s5,  // msout
                                                    const float* __restrict__ s6,  // ffn1
                                                    const float* __restrict__ s7,  // ffn2
                                                    u16* __restrict__ Wb) {
    int i8 = (blockIdx.x * 256 + threadIdx.x) * 8;
    if (i8 >= WTOTAL) return;
    const float* src; int rel;
    if      (i8 < WOFF_OUTPROJ) { src = s0; rel = i8; }
    else if (i8 < WOFF_VALPROJ) { src = s1; rel = i8 - WOFF_OUTPROJ; }
    else if (i8 < WOFF_SAMP)    { src = s2; rel = i8 - WOFF_VALPROJ; }
    else if (i8 < WOFF_ATTW)    { src = s3; rel = i8 - WOFF_SAMP; }
    else if (i8 < WOFF_MSOUT)   { src = s4; rel = i8 - WOFF_ATTW; }
    else if (i8 < WOFF_FFN1)    { src = s5; rel = i8 - WOFF_MSOUT; }
    else if (i8 < WOFF_FFN2)    { src = s6; rel = i8 - WOFF_FFN1; }
    else                        { src = s7; rel = i8 - WOFF_FFN2; }
    float4 v0 = *(const float4*)(src + rel);
    float4 v1 = *(const float4*)(src + rel + 4);
    short o[8];
    o[0] = f2bf(v0.x); o[1] = f2bf(v0.y); o[2] = f2bf(v0.z); o[3] = f2bf(v0.w);
    o[4] = f2bf(v1.x); o[5] = f2bf(v1.y); o[6] = f2bf(v1.z); o[7] = f2bf(v1.w);
    *(bf16x8*)(Wb + i8) = *(bf16x8*)o;
}

// ---------------------------------------------------------------------------
// fused add -> bf16 (and optional bf16 copy of input a)
// ---------------------------------------------------------------------------
__global__ __launch_bounds__(256) void add_bf16_kernel(const float* __restrict__ a,
                                                       const float* __restrict__ b,
                                                       u16* __restrict__ osum,
                                                       u16* __restrict__ oa,
                                                       size_t n4) {
    size_t i = (size_t)blockIdx.x * blockDim.x + threadIdx.x;
    if (i >= n4) return;
    float4 x = ((const float4*)a)[i];
    float4 y = ((const float4*)b)[i];
    ushort4 s;
    s.x = (u16)f2bf(x.x + y.x); s.y = (u16)f2bf(x.y + y.y);
    s.z = (u16)f2bf(x.z + y.z); s.w = (u16)f2bf(x.w + y.w);
    ((ushort4*)osum)[i] = s;
    if (oa) {
        ushort4 q;
        q.x = (u16)f2bf(x.x); q.y = (u16)f2bf(x.y);
        q.z = (u16)f2bf(x.z); q.w = (u16)f2bf(x.w);
        ((ushort4*)oa)[i] = q;
    }
}

// ---------------------------------------------------------------------------
// pipelined bf16 MFMA GEMM: C[M,N] = A[M,K] @ W[N,K]^T + bias (+res f32)(+relu)
// W is PRE-CONVERTED bf16. A: f32 (convert in staging) or bf16.
// 128x128 tile, BK=32, 256 thr (4 waves 2x2), double-buffered LDS,
// ONE barrier per K-step: ds_write buf[cur] | prefetch t+1 | barrier | MFMA buf[cur].
// read(buf[cur],t) and write(buf[cur],t+2) are separated by two barriers -> safe.
// ---------------------------------------------------------------------------
#define LDK 40
template <typename TA, typename TC>
__global__ __launch_bounds__(256) void gemm2_kernel(const TA* __restrict__ A,
                                                    const u16* __restrict__ W,
                                                    const float* __restrict__ bias,
                                                    const float* __restrict__ res,
                                                    TC* __restrict__ C,
                                                    int M, int N, int K, int relu) {
    __shared__ __align__(16) u16 As[2][128 * LDK];
    __shared__ __align__(16) u16 Bs[2][128 * LDK];

    const int n0 = blockIdx.x * 128;
    const int m0 = blockIdx.y * 128;
    const int t  = threadIdx.x;

    const int srow = t >> 1;
    const int scol = (t & 1) << 4;

    const int lane = t & 63;
    const int lr   = lane & 15;
    const int kg   = lane >> 4;
    const int wid  = t >> 6;
    const int wr   = wid >> 1;
    const int wc   = wid & 1;

    f32x4 acc[4][4] = {};

    const int  nk  = K >> 5;
    const int  gm  = m0 + srow;
    const bool mok = (gm < M);

    const float* af32 = (const float*)A + (size_t)(mok ? gm : 0) * K + scol;
    const u16*   ab16 = (const u16*)A + (size_t)(mok ? gm : 0) * K + scol;
    const u16*   wp   = W + (size_t)(n0 + srow) * K + scol;

    // prefetch registers
    float4 af[4];
    bf16x8 ab[2];
    bf16x8 wf[2];

    // ---- prologue: load k-step 0 ----
    if constexpr (sizeof(TA) == 4) {
        if (mok) {
            #pragma unroll
            for (int q = 0; q < 4; ++q) af[q] = *(const float4*)(af32 + q * 4);
        } else {
            #pragma unroll
            for (int q = 0; q < 4; ++q) af[q] = make_float4(0.f, 0.f, 0.f, 0.f);
        }
    } else {
        if (mok) { ab[0] = *(const bf16x8*)ab16; ab[1] = *(const bf16x8*)(ab16 + 8); }
        else {
            #pragma unroll
            for (int q = 0; q < 8; ++q) { ab[0][q] = 0; ab[1][q] = 0; }
        }
    }
    wf[0] = *(const bf16x8*)wp;
    wf[1] = *(const bf16x8*)(wp + 8);

    for (int kt = 0; kt < nk; ++kt) {
        const int cur = kt & 1;
        // ---- store staged regs to LDS buf[cur] ----
        if constexpr (sizeof(TA) == 4) {
            short tmp[16];
            #pragma unroll
            for (int q = 0; q < 4; ++q) {
                tmp[q * 4 + 0] = f2bf(af[q].x);
                tmp[q * 4 + 1] = f2bf(af[q].y);
                tmp[q * 4 + 2] = f2bf(af[q].z);
                tmp[q * 4 + 3] = f2bf(af[q].w);
            }
            *(bf16x8*)&As[cur][srow * LDK + scol]     = *(bf16x8*)tmp;
            *(bf16x8*)&As[cur][srow * LDK + scol + 8] = *(bf16x8*)(tmp + 8);
        } else {
            *(bf16x8*)&As[cur][srow * LDK + scol]     = ab[0];
            *(bf16x8*)&As[cur][srow * LDK + scol + 8] = ab[1];
        }
        *(bf16x8*)&Bs[cur][srow * LDK + scol]     = wf[0];
        *(bf16x8*)&Bs[cur][srow * LDK + scol + 8] = wf[1];

        // ---- prefetch k-step kt+1 ----
        if (kt + 1 < nk) {
            const int k1 = (kt + 1) << 5;
            if constexpr (sizeof(TA) == 4) {
                if (mok) {
                    #pragma unroll
                    for (int q = 0; q < 4; ++q) af[q] = *(const float4*)(af32 + k1 + q * 4);
                }
            } else {
                if (mok) {
                    ab[0] = *(const bf16x8*)(ab16 + k1);
                    ab[1] = *(const bf16x8*)(ab16 + k1 + 8);
                }
            }
            wf[0] = *(const bf16x8*)(wp + k1);
            wf[1] = *(const bf16x8*)(wp + k1 + 8);
        }

        __syncthreads();

        // ---- MFMA from buf[cur] ----
        const u16* pA = &As[cur][(wr * 64 + lr) * LDK + kg * 8];
        const u16* pB = &Bs[cur][(wc * 64 + lr) * LDK + kg * 8];
        bf16x8 a[4], b[4];
        #pragma unroll
        for (int i = 0; i < 4; ++i) a[i] = *(const bf16x8*)(pA + i * 16 * LDK);
        #pragma unroll
        for (int j = 0; j < 4; ++j) b[j] = *(const bf16x8*)(pB + j * 16 * LDK);
        #pragma unroll
        for (int i = 0; i < 4; ++i)
            #pragma unroll
            for (int j = 0; j < 4; ++j)
                acc[i][j] = __builtin_amdgcn_mfma_f32_16x16x32_bf16(a[i], b[j], acc[i][j], 0, 0, 0);
    }

    // epilogue: D row = kg*4 + r, col = lr
    #pragma unroll
    for (int i = 0; i < 4; ++i) {
        #pragma unroll
        for (int j = 0; j < 4; ++j) {
            const int n = n0 + wc * 64 + j * 16 + lr;
            const float bn = bias[n];
            #pragma unroll
            for (int r = 0; r < 4; ++r) {
                const int m = m0 + wr * 64 + i * 16 + kg * 4 + r;
                if (m < M) {
                    float v = acc[i][j][r] + bn;
                    if (res)  v += res[(size_t)m * N + n];
                    if (relu) v = fmaxf(v, 0.f);
                    if constexpr (sizeof(TC) == 4) C[(size_t)m * N + n] = v;
                    else                           C[(size_t)m * N + n] = (TC)(u16)f2bf(v);
                }
            }
        }
    }
}

// ---------------------------------------------------------------------------
// MFMA flash attention (unchanged from round 2/5 — verified)
// ---------------------------------------------------------------------------
#define LDA2 40
#define LDP  72
__global__ __launch_bounds__(256) void attn_mfma_kernel(const u16* __restrict__ Qg,
                                                        const u16* __restrict__ Kg,
                                                        const u16* __restrict__ Vg,
                                                        u16* __restrict__ Og) {
    __shared__ __align__(16) u16 Ks[64 * LDA2];
    __shared__ __align__(16) u16 Vs[64 * LDA2];
    __shared__ __align__(16) u16 Ps[4][16 * LDP];

    const int qt = blockIdx.x, h = blockIdx.y, b = blockIdx.z;
    const int t  = threadIdx.x;
    const int wq = t >> 6;
    const int lane = t & 63;
    const int l15  = lane & 15;
    const int g    = lane >> 4;
    const int q0   = qt * 64;

    const int srow = t >> 2;
    const int sd   = (t & 3) * 8;

    int qrow = q0 + wq * 16 + l15;
    if (qrow > LQ_ - 1) qrow = LQ_ - 1;
    const bf16x8 qfrag = *(const bf16x8*)(Qg + ((size_t)(b * LQ_) + qrow) * D_ + h * HD_ + g * 8);

    float m_i = -1e30f, l_i = 0.f;
    f32x4 o_acc[2] = {};
    const float scale = 0.17677669529663687f;

    for (int k0 = 0; k0 < 960; k0 += 64) {
        {
            int kr = k0 + srow;
            bf16x8 kv, vv;
            if (kr < LQ_) {
                kv = *(const bf16x8*)(Kg + ((size_t)(b * LQ_) + kr) * D_ + h * HD_ + sd);
                vv = *(const bf16x8*)(Vg + ((size_t)(b * LQ_) + kr) * D_ + h * HD_ + sd);
            } else {
                #pragma unroll
                for (int j = 0; j < 8; ++j) { kv[j] = 0; vv[j] = 0; }
            }
            *(bf16x8*)&Ks[srow * LDA2 + sd] = kv;
            *(bf16x8*)&Vs[srow * LDA2 + sd] = vv;
        }
        __syncthreads();

        float p[4][4];
        float tmax = -1e30f;
        #pragma unroll
        for (int kt = 0; kt < 4; ++kt) {
            bf16x8 af = *(const bf16x8*)&Ks[(kt * 16 + l15) * LDA2 + g * 8];
            f32x4 c = {0.f, 0.f, 0.f, 0.f};
            c = __builtin_amdgcn_mfma_f32_16x16x32_bf16(af, qfrag, c, 0, 0, 0);
            #pragma unroll
            for (int r = 0; r < 4; ++r) {
                int kglob = k0 + kt * 16 + g * 4 + r;
                float s = (kglob < LQ_) ? c[r] * scale : -1e30f;
                p[kt][r] = s;
                tmax = fmaxf(tmax, s);
            }
        }
        tmax = fmaxf(tmax, __shfl_xor(tmax, 16));
        tmax = fmaxf(tmax, __shfl_xor(tmax, 32));
        float newm = fmaxf(m_i, tmax);
        float corr = __expf(m_i - newm);
        float rs = 0.f;
        #pragma unroll
        for (int kt = 0; kt < 4; ++kt) {
            #pragma unroll
            for (int r = 0; r < 4; ++r) {
                float e = __expf(p[kt][r] - newm);
                p[kt][r] = e;
                rs += e;
            }
            ushort4 pk;
            pk.x = (u16)f2bf(p[kt][0]);
            pk.y = (u16)f2bf(p[kt][1]);
            pk.z = (u16)f2bf(p[kt][2]);
            pk.w = (u16)f2bf(p[kt][3]);
            *(ushort4*)&Ps[wq][l15 * LDP + kt * 16 + g * 4] = pk;
        }
        rs += __shfl_xor(rs, 16);
        rs += __shfl_xor(rs, 32);
        l_i = l_i * corr + rs;
        m_i = newm;

        #pragma unroll
        for (int r = 0; r < 4; ++r) {
            float cq = __shfl(corr, g * 4 + r);
            o_acc[0][r] *= cq;
            o_acc[1][r] *= cq;
        }

        #pragma unroll
        for (int c = 0; c < 2; ++c) {
            bf16x8 pa = *(const bf16x8*)&Ps[wq][l15 * LDP + c * 32 + g * 8];
            #pragma unroll
            for (int nt = 0; nt < 2; ++nt) {
                short vv[8];
                #pragma unroll
                for (int j = 0; j < 8; ++j)
                    vv[j] = (short)Vs[(c * 32 + g * 8 + j) * LDA2 + nt * 16 + l15];
                o_acc[nt] = __builtin_amdgcn_mfma_f32_16x16x32_bf16(pa, *(bf16x8*)vv, o_acc[nt], 0, 0, 0);
            }
        }
        __syncthreads();
    }

    float il = 1.f / l_i;
    #pragma unroll
    for (int r = 0; r < 4; ++r) {
        float ilq = __shfl(il, g * 4 + r);
        int q = q0 + wq * 16 + g * 4 + r;
        if (q < LQ_) {
            u16* dst = Og + ((size_t)(b * LQ_) + q) * D_ + h * HD_ + l15;
            dst[0]  = (u16)f2bf(o_acc[0][r] * ilq);
            dst[16] = (u16)f2bf(o_acc[1][r] * ilq);
        }
    }
}

// ---------------------------------------------------------------------------
// LayerNorm over D=256; optional bf16 second output
// ---------------------------------------------------------------------------
__global__ __launch_bounds__(256) void ln_kernel(const float* __restrict__ X,
                                                 const float* __restrict__ g,
                                                 const float* __restrict__ bb,
                                                 float* __restrict__ Y,
                                                 u16* __restrict__ Yb, int M) {
    int row  = blockIdx.x * 4 + (threadIdx.x >> 6);
    int lane = threadIdx.x & 63;
    if (row >= M) return;
    const float* x = X + (size_t)row * D_;
    float4 v = *(const float4*)(x + lane * 4);
    float s = v.x + v.y + v.z + v.w;
    #pragma unroll
    for (int o = 32; o >= 1; o >>= 1) s += __shfl_xor(s, o);
    float mean = s * (1.f / D_);
    float dx0 = v.x - mean, dx1 = v.y - mean, dx2 = v.z - mean, dx3 = v.w - mean;
    float ss = dx0 * dx0 + dx1 * dx1 + dx2 * dx2 + dx3 * dx3;
    #pragma unroll
    for (int o = 32; o >= 1; o >>= 1) ss += __shfl_xor(ss, o);
    float rstd = rsqrtf(ss * (1.f / D_) + 1e-5f);
    float4 gv = *(const float4*)(g + lane * 4);
    float4 bv = *(const float4*)(bb + lane * 4);
    float4 out;
    out.x = dx0 * rstd * gv.x + bv.x;
    out.y = dx1 * rstd * gv.y + bv.y;
    out.z = dx2 * rstd * gv.z + bv.z;
    out.w = dx3 * rstd * gv.w + bv.w;
    *(float4*)(Y + (size_t)row * D_ + lane * 4) = out;
    if (Yb) {
        ushort4 ob;
        ob.x = (u16)f2bf(out.x); ob.y = (u16)f2bf(out.y);
        ob.z = (u16)f2bf(out.z); ob.w = (u16)f2bf(out.w);
        *(ushort4*)(Yb + (size_t)row * D_ + lane * 4) = ob;
    }
}

// ---------------------------------------------------------------------------
// softmax over 16 contiguous elems per row
// ---------------------------------------------------------------------------
__global__ __launch_bounds__(256) void softmax16_kernel(const float* __restrict__ X,
                                                        float* __restrict__ Y,
                                                        int rows) {
    int r = blockIdx.x * blockDim.x + threadIdx.x;
    if (r >= rows) return;
    const float* x = X + (size_t)r * 16;
    float m = -1e30f;
    #pragma unroll
    for (int i = 0; i < 16; ++i) m = fmaxf(m, x[i]);
    float e[16], s = 0.f;
    #pragma unroll
    for (int i = 0; i < 16; ++i) { e[i] = expf(x[i] - m); s += e[i]; }
    float inv = 1.f / s;
    float* y = Y + (size_t)r * 16;
    #pragma unroll
    for (int i = 0; i < 16; ++i) y[i] = e[i] * inv;
}

// ---------------------------------------------------------------------------
// multi-scale deformable sampling, vectorized: one thread per (b,q,h, 8 dims)
// corner gathers are 16B bf16x8 loads; lanes 4k..4k+3 share (b,q,h).
// output bf16 (feeds msout GEMM).
// ---------------------------------------------------------------------------
__global__ __launch_bounds__(256) void msdeform2_kernel(const u16* __restrict__ value,
                                                        const float* __restrict__ ref,
                                                        const float* __restrict__ off,
                                                        const float* __restrict__ attw,
                                                        u16* __restrict__ out) {
    const int levH[4] = {128, 64, 32, 16};
    const int levW[4] = {128, 64, 32, 16};
    const int levS[4] = {0, 16384, 20480, 21504};

    int gid = blockIdx.x * 256 + threadIdx.x;     // B*LQ*NH*4 = 460800
    int d8  = gid & 3;
    int bqh = gid >> 2;
    int h   = bqh & (NH_ - 1);
    int bq  = bqh >> 3;
    int b   = bq / LQ_;

    const float* refp = ref  + (size_t)bq * NL_ * 2;
    const float* offp = off  + (size_t)bq * 256 + h * 32;
    const float* awp  = attw + (size_t)bq * 128 + h * 16;
    const u16* vbase  = value + (size_t)b * LIN_ * D_ + h * HD_ + d8 * 8;

    float acc[8] = {};
    #pragma unroll
    for (int l = 0; l < NL_; ++l) {
        float rx = refp[l * 2 + 0], ry = refp[l * 2 + 1];
        const int wl = levW[l], hl = levH[l];
        const u16* vlev = vbase + (size_t)levS[l] * D_;
        #pragma unroll
        for (int p = 0; p < NP_; ++p) {
            float ox = offp[(l * NP_ + p) * 2 + 0];
            float oy = offp[(l * NP_ + p) * 2 + 1];
            float x = rx * wl + ox - 0.5f;
            float y = ry * hl + oy - 0.5f;
            float x0f = floorf(x), y0f = floorf(y);
            float fx = x - x0f, fy = y - y0f;
            int x0 = (int)x0f, y0 = (int)y0f;
            float aw = awp[l * NP_ + p];
            #pragma unroll
            for (int dy = 0; dy < 2; ++dy) {
                int   yi = y0 + dy;
                float wy = dy ? fy : 1.f - fy;
                bool  vy = (yi >= 0) && (yi < hl);
                int   yc = min(max(yi, 0), hl - 1);
                #pragma unroll
                for (int dx = 0; dx < 2; ++dx) {
                    int   xi = x0 + dx;
                    float wx = dx ? fx : 1.f - fx;
                    bool  vx = (xi >= 0) && (xi < wl);
                    int   xc = min(max(xi, 0), wl - 1);
                    float w  = (vx && vy) ? aw * wy * wx : 0.f;
                    bf16x8 v = *(const bf16x8*)(vlev + (size_t)(yc * wl + xc) * D_);
                    #pragma unroll
                    for (int j = 0; j < 8; ++j)
                        acc[j] += w * bf2f((u16)v[j]);
                }
            }
        }
    }
    short o[8];
    #pragma unroll
    for (int j = 0; j < 8; ++j) o[j] = f2bf(acc[j]);
    *(bf16x8*)(out + (size_t)bq * D_ + h * HD_ + d8 * 8) = *(bf16x8*)o;
}

// ---------------------------------------------------------------------------
extern "C" void kernel_launch(void* const* d_in, const int* in_sizes, int n_in,
                              void* d_out, int out_size, void* d_ws, size_t ws_size,
                              hipStream_t stream) {
    const float* queries      = (const float*)d_in[0];
    const float* features     = (const float*)d_in[1];
    const float* refpts       = (const float*)d_in[2];
    const float* q_pos        = (const float*)d_in[3];
    const float* in_proj_w    = (const float*)d_in[4];
    const float* in_proj_b    = (const float*)d_in[5];
    const float* out_proj_w   = (const float*)d_in[6];
    const float* out_proj_b   = (const float*)d_in[7];
    const float* value_proj_w = (const float*)d_in[8];
    const float* value_proj_b = (const float*)d_in[9];
    const float* samp_w       = (const float*)d_in[10];
    const float* samp_b       = (const float*)d_in[11];
    const float* attw_w       = (const float*)d_in[12];
    const float* attw_b       = (const float*)d_in[13];
    const float* msout_w      = (const float*)d_in[14];
    const float* msout_b      = (const float*)d_in[15];
    const float* ffn_w1       = (const float*)d_in[16];
    const float* ffn_b1       = (const float*)d_in[17];
    const float* ffn_w2       = (const float*)d_in[18];
    const float* ffn_b2       = (const float*)d_in[19];
    const float* ln1_g        = (const float*)d_in[20];
    const float* ln1_b        = (const float*)d_in[21];
    const float* ln2_g        = (const float*)d_in[22];
    const float* ln2_b        = (const float*)d_in[23];
    const float* ln3_g        = (const float*)d_in[24];
    const float* ln3_b        = (const float*)d_in[25];

    float* ws = (float*)d_ws;
    const size_t NQ = (size_t)B_ * LQ_ * D_;          // 3,686,400
    // f32 scratch
    float* bufB = ws;                                  // proj outs (pre-LN), samp
    float* bufC = ws + NQ;                             // attw logits / LN2 f32
    float* bufF = ws + 2 * NQ;                         // x (post-LN1)
    float* bufD = ws + 3 * NQ;                         // attw softmax
    // bf16 scratch
    u16* U    = (u16*)(ws + 4 * NQ);
    u16* qkb  = U;                                     // bf16(queries+q_pos)
    u16* qb   = U + NQ;                                // bf16(queries)
    u16* q2b  = U + 2 * NQ;                            // bf16(x+q_pos)
    u16* Qb   = U + 3 * NQ;
    u16* Kb   = U + 4 * NQ;
    u16* Vb   = U + 5 * NQ;
    u16* Ob   = U + 6 * NQ;
    u16* MSb  = U + 7 * NQ;                            // msdeform out
    u16* LN2b = U + 8 * NQ;
    u16* VALb = U + 9 * NQ;                            // (B, LIN, D)
    u16* H1b  = VALb + (size_t)B_ * LIN_ * D_;         // (B*LQ, DFFN)
    u16* Wb   = H1b + (size_t)B_ * LQ_ * DFFN_;        // all weights bf16

    const int M  = B_ * LQ_;          // 14400
    const int MV = B_ * LIN_;         // 348160
    const int GY = (M + 127) / 128;   // 113

    // 0. weight prep (bf16)
    wprep_kernel<<<752, 256, 0, stream>>>(in_proj_w, out_proj_w, value_proj_w, samp_w,
                                          attw_w, msout_w, ffn_w1, ffn_w2, Wb);

    // 1. qkb = bf16(queries + q_pos); qb = bf16(queries)
    add_bf16_kernel<<<3600, 256, 0, stream>>>(queries, q_pos, qkb, qb, NQ / 4);

    // 2. Q, K (from qkb), V (from qb)
    gemm2_kernel<u16, u16><<<dim3(2, GY), 256, 0, stream>>>(qkb, Wb + WOFF_INPROJ,          in_proj_b,       nullptr, Qb, M, 256, 256, 0);
    gemm2_kernel<u16, u16><<<dim3(2, GY), 256, 0, stream>>>(qkb, Wb + WOFF_INPROJ + 65536,  in_proj_b + 256, nullptr, Kb, M, 256, 256, 0);
    gemm2_kernel<u16, u16><<<dim3(2, GY), 256, 0, stream>>>(qb,  Wb + WOFF_INPROJ + 131072, in_proj_b + 512, nullptr, Vb, M, 256, 256, 0);

    // 3. MFMA flash attention -> Ob
    attn_mfma_kernel<<<dim3(15, NH_, B_), 256, 0, stream>>>(Qb, Kb, Vb, Ob);

    // 4. out-proj + residual(queries) -> bufB; 5. LN1 -> bufF
    gemm2_kernel<u16, float><<<dim3(2, GY), 256, 0, stream>>>(Ob, Wb + WOFF_OUTPROJ, out_proj_b, queries, bufB, M, 256, 256, 0);
    ln_kernel<<<3600, 256, 0, stream>>>(bufB, ln1_g, ln1_b, bufF, nullptr, M);

    // 6. q2b = bf16(x + q_pos)
    add_bf16_kernel<<<3600, 256, 0, stream>>>(bufF, q_pos, q2b, nullptr, NQ / 4);

    // 7. value projection (f32 A, pipelined conversion) -> VALb
    gemm2_kernel<float, u16><<<dim3(2, MV / 128), 256, 0, stream>>>(features, Wb + WOFF_VALPROJ, value_proj_b, nullptr, VALb, MV, 256, 256, 0);

    // 8. sampling offsets (bufB) and attention-weight logits (bufC)
    gemm2_kernel<u16, float><<<dim3(2, GY), 256, 0, stream>>>(q2b, Wb + WOFF_SAMP, samp_b, nullptr, bufB, M, 256, 256, 0);
    gemm2_kernel<u16, float><<<dim3(1, GY), 256, 0, stream>>>(q2b, Wb + WOFF_ATTW, attw_b, nullptr, bufC, M, 128, 256, 0);

    // 9. softmax over 16 -> bufD
    softmax16_kernel<<<450, 256, 0, stream>>>(bufC, bufD, B_ * LQ_ * NH_);

    // 10. deformable sampling -> MSb (bf16)
    msdeform2_kernel<<<1800, 256, 0, stream>>>(VALb, refpts, bufB, bufD, MSb);

    // 11. msout + residual(x) -> bufB; 12. LN2 -> bufC (f32) + LN2b (bf16)
    gemm2_kernel<u16, float><<<dim3(2, GY), 256, 0, stream>>>(MSb, Wb + WOFF_MSOUT, msout_b, bufF, bufB, M, 256, 256, 0);
    ln_kernel<<<3600, 256, 0, stream>>>(bufB, ln2_g, ln2_b, bufC, LN2b, M);

    // 13. FFN up + ReLU -> H1b
    gemm2_kernel<u16, u16><<<dim3(16, GY), 256, 0, stream>>>(LN2b, Wb + WOFF_FFN1, ffn_b1, nullptr, H1b, M, 2048, 256, 1);

    // 14. FFN down + residual(bufC) -> bufB; 15. LN3 -> d_out
    gemm2_kernel<u16, float><<<dim3(2, GY), 256, 0, stream>>>(H1b, Wb + WOFF_FFN2, ffn_b2, bufC, bufB, M, 256, 2048, 0);
    ln_kernel<<<3600, 256, 0, stream>>>(bufB, ln3_g, ln3_b, (float*)d_out, nullptr, M);
}